// Round 2
// baseline (415.570 us; speedup 1.0000x reference)
//
#include <hip/hip_runtime.h>

// Problem constants (from reference setup_inputs): B=8, S=2048, H=1024
#define BB 8
#define SS 2048
#define HH 1024

// Native clang vector type — __builtin_nontemporal_store requires this
// (HIP's float4 is a class and is rejected).
typedef float vf4 __attribute__((ext_vector_type(4)));

// ---------------------------------------------------------------------------
// Kernel 1: per-token phase. One wave handles 4 consecutive tokens; weights
// (16 KB of Ws/We) are preloaded into registers once per wave and reused, so
// per-token work is just 4 coalesced float4 rep loads + fp64 FMAs.
// Math is bit-identical to the previously passing version (same accumulation
// order, fp64, same butterfly reduce) so boundary decisions don't move.
// Emits ss[token] = start_cand ? score_s : -1e30 (same for se/end).
// ---------------------------------------------------------------------------
__global__ __launch_bounds__(256) void token_kernel(
    const float* __restrict__ rep, const int* __restrict__ mask,
    const float* __restrict__ Ws, const float* __restrict__ bs,
    const float* __restrict__ We, const float* __restrict__ be,
    const float* __restrict__ Wm, const float* __restrict__ bm,
    float* __restrict__ ss, float* __restrict__ se)
{
    const int wave = threadIdx.x >> 6;
    const int lane = threadIdx.x & 63;
    const int tok0 = blockIdx.x * 16 + wave * 4;   // 4 tokens per wave

    // Preload this lane's weight slice: Ws/We are (H,2) row-major, so
    // features h..h+3 occupy floats [2h, 2h+8).
    float4 w0[4], w1[4], e0[4], e1[4];
    #pragma unroll
    for (int k = 0; k < 4; ++k) {
        const int h = k * 256 + lane * 4;
        w0[k] = *(const float4*)(Ws + 2 * h);
        w1[k] = *(const float4*)(Ws + 2 * h + 4);
        e0[k] = *(const float4*)(We + 2 * h);
        e1[k] = *(const float4*)(We + 2 * h + 4);
    }

    #pragma unroll
    for (int t = 0; t < 4; ++t) {
        const int token = tok0 + t;
        const float* r = rep + (size_t)token * HH;

        double a0 = 0.0, a1 = 0.0, a2 = 0.0, a3 = 0.0;
        #pragma unroll
        for (int k = 0; k < 4; ++k) {
            const float4 rv = *(const float4*)(r + k * 256 + lane * 4);
            a0 += (double)rv.x * w0[k].x + (double)rv.y * w0[k].z + (double)rv.z * w1[k].x + (double)rv.w * w1[k].z;
            a1 += (double)rv.x * w0[k].y + (double)rv.y * w0[k].w + (double)rv.z * w1[k].y + (double)rv.w * w1[k].w;
            a2 += (double)rv.x * e0[k].x + (double)rv.y * e0[k].z + (double)rv.z * e1[k].x + (double)rv.w * e1[k].z;
            a3 += (double)rv.x * e0[k].y + (double)rv.y * e0[k].w + (double)rv.z * e1[k].y + (double)rv.w * e1[k].w;
        }

        // wave-64 butterfly reduce (4 accumulators)
        #pragma unroll
        for (int off = 32; off >= 1; off >>= 1) {
            a0 += __shfl_down(a0, off);
            a1 += __shfl_down(a1, off);
            a2 += __shfl_down(a2, off);
            a3 += __shfl_down(a3, off);
        }

        if (lane == 0) {
            const double sl0 = a0 + (double)bs[0];
            const double sl1 = a1 + (double)bs[1];
            const double el0 = a2 + (double)be[0];
            const double el1 = a3 + (double)be[1];
            const bool m  = (mask[token] != 0);
            const bool sc = m && (sl0 <= sl1);
            const bool ec = m && (el0 <= el1);
            const double sv = sl0 * (double)Wm[0] + sl1 * (double)Wm[1];
            const double ev = el0 * (double)Wm[2] + el1 * (double)Wm[3];
            ss[token] = sc ? (float)sv : -1e30f;   // sentinel: pair>0 impossible
            se[token] = ec ? (float)ev : -1e30f;
        }
    }
}

// ---------------------------------------------------------------------------
// Kernel 2: pair phase. Pure store-bound: 268 MB of writes.
// Persistent-style: 2048 blocks (8/CU, full 32 waves/CU occupancy). Each
// block owns 8 consecutive rows (same batch b since 2048 % 8 == 0); each
// thread owns 8 consecutive j, holds its se slice in registers across all
// 8 rows, and issues 32 nontemporal dwordx4 stores over its lifetime —
// deep store pipelining instead of 2-store fire-and-die threads.
// ---------------------------------------------------------------------------
__global__ __launch_bounds__(256) void pair_kernel(
    const float* __restrict__ ss, const float* __restrict__ se,
    const float* __restrict__ bm,
    float* __restrict__ out_valid, float* __restrict__ out_score)
{
    const int row0 = blockIdx.x * 8;           // 8 rows per block
    const int b    = row0 >> 11;               // rows 0..2047 -> b=0, etc.
    const int j0   = threadIdx.x * 8;          // 8 consecutive j per thread
    const float bmv = bm[0];

    // This thread's end-score slice, reused for all 8 rows.
    const float4 e0 = *(const float4*)(se + b * SS + j0);
    const float4 e1 = *(const float4*)(se + b * SS + j0 + 4);
    const float ev[8] = {e0.x, e0.y, e0.z, e0.w, e1.x, e1.y, e1.z, e1.w};

    #pragma unroll
    for (int r = 0; r < 8; ++r) {
        const int row = row0 + r;
        const int i   = row & (SS - 1);
        const float s_i = ss[row];             // uniform -> scalar load

        float va[8], pa[8];
        #pragma unroll
        for (int c = 0; c < 8; ++c) {
            // match reference add order: (score_s + score_e) + bm
            const float p = (s_i + ev[c]) + bmv;
            const bool  v = (i <= j0 + c) && (p > 0.0f);
            va[c] = v ? 1.0f : 0.0f;
            pa[c] = v ? p    : 0.0f;
        }

        const size_t off = (size_t)row * SS + j0;
        vf4 vv0 = {va[0], va[1], va[2], va[3]};
        vf4 vv1 = {va[4], va[5], va[6], va[7]};
        vf4 pv0 = {pa[0], pa[1], pa[2], pa[3]};
        vf4 pv1 = {pa[4], pa[5], pa[6], pa[7]};
        __builtin_nontemporal_store(vv0, (vf4*)(out_valid + off));
        __builtin_nontemporal_store(vv1, (vf4*)(out_valid + off + 4));
        __builtin_nontemporal_store(pv0, (vf4*)(out_score + off));
        __builtin_nontemporal_store(pv1, (vf4*)(out_score + off + 4));
    }
}

extern "C" void kernel_launch(void* const* d_in, const int* in_sizes, int n_in,
                              void* d_out, int out_size, void* d_ws, size_t ws_size,
                              hipStream_t stream) {
    const float* rep  = (const float*)d_in[0];
    const int*   mask = (const int*)  d_in[1];
    const float* Ws   = (const float*)d_in[2];
    const float* bs   = (const float*)d_in[3];
    const float* We   = (const float*)d_in[4];
    const float* be   = (const float*)d_in[5];
    const float* Wm   = (const float*)d_in[6];
    const float* bm   = (const float*)d_in[7];

    float* ss = (float*)d_ws;            // B*S floats
    float* se = ss + BB * SS;            // B*S floats (total 128 KB of ws)

    float* out_valid = (float*)d_out;                          // B*S*S floats
    float* out_score = out_valid + (size_t)BB * SS * SS;       // B*S*S floats

    // Phase 1: 16384 tokens, 4 tokens/wave, 4 waves/block -> 1024 blocks
    token_kernel<<<BB * SS / 16, 256, 0, stream>>>(rep, mask, Ws, bs, We, be,
                                                   Wm, bm, ss, se);

    // Phase 2: 16384 rows, 8 rows/block -> 2048 blocks x 256 threads
    pair_kernel<<<BB * SS / 8, 256, 0, stream>>>(ss, se, bm,
                                                 out_valid, out_score);
}

// Round 3
// 327.964 us; speedup vs baseline: 1.2671x; 1.2671x over previous
//
#include <hip/hip_runtime.h>

// Problem constants (from reference setup_inputs): B=8, S=2048, H=1024
#define BB 8
#define SS 2048
#define HH 1024

// ---------------------------------------------------------------------------
// Kernel 1: per-token phase (round-0 proven version, bit-identical math).
// One wave (64 lanes) per token; block = 4 waves. Computes start/end logits
// (4 dots of length H), candidacy, scores. Emits ss[token] = start_cand ?
// score_s : -1e30 sentinel (same for se/end) so the pair kernel needs no
// boolean arrays. fp64 accumulation: the pair>0 / sl0<=sl1 sign thresholds
// are hard cutoffs; stay as close to the fp64 numpy reference as possible.
// ---------------------------------------------------------------------------
__global__ __launch_bounds__(256) void token_kernel(
    const float* __restrict__ rep, const int* __restrict__ mask,
    const float* __restrict__ Ws, const float* __restrict__ bs,
    const float* __restrict__ We, const float* __restrict__ be,
    const float* __restrict__ Wm, const float* __restrict__ bm,
    float* __restrict__ ss, float* __restrict__ se)
{
    const int token = blockIdx.x * 4 + (threadIdx.x >> 6);
    const int lane  = threadIdx.x & 63;
    const float* r = rep + (size_t)token * HH;

    double a0 = 0.0, a1 = 0.0, a2 = 0.0, a3 = 0.0;
    #pragma unroll
    for (int k = 0; k < HH / 256; ++k) {
        const int h = k * 256 + lane * 4;           // 4 consecutive features
        const float4 rv = *(const float4*)(r + h);
        // Ws/We are (H,2) row-major: [h][0],[h][1] interleaved
        const float4 w0 = *(const float4*)(Ws + 2 * h);      // h, h+1
        const float4 w1 = *(const float4*)(Ws + 2 * h + 4);  // h+2, h+3
        const float4 e0 = *(const float4*)(We + 2 * h);
        const float4 e1 = *(const float4*)(We + 2 * h + 4);
        a0 += (double)rv.x * w0.x + (double)rv.y * w0.z + (double)rv.z * w1.x + (double)rv.w * w1.z;
        a1 += (double)rv.x * w0.y + (double)rv.y * w0.w + (double)rv.z * w1.y + (double)rv.w * w1.w;
        a2 += (double)rv.x * e0.x + (double)rv.y * e0.z + (double)rv.z * e1.x + (double)rv.w * e1.z;
        a3 += (double)rv.x * e0.y + (double)rv.y * e0.w + (double)rv.z * e1.y + (double)rv.w * e1.w;
    }
    // wave-64 butterfly reduce (4 accumulators)
    #pragma unroll
    for (int off = 32; off >= 1; off >>= 1) {
        a0 += __shfl_down(a0, off);
        a1 += __shfl_down(a1, off);
        a2 += __shfl_down(a2, off);
        a3 += __shfl_down(a3, off);
    }
    if (lane == 0) {
        const double sl0 = a0 + (double)bs[0];
        const double sl1 = a1 + (double)bs[1];
        const double el0 = a2 + (double)be[0];
        const double el1 = a3 + (double)be[1];
        const bool m  = (mask[token] != 0);
        const bool sc = m && (sl0 <= sl1);
        const bool ec = m && (el0 <= el1);
        const double sv = sl0 * (double)Wm[0] + sl1 * (double)Wm[1];
        const double ev = el0 * (double)Wm[2] + el1 * (double)Wm[3];
        ss[token] = sc ? (float)sv : -1e30f;   // sentinel: pair>0 impossible
        se[token] = ec ? (float)ev : -1e30f;
    }
}

// ---------------------------------------------------------------------------
// Kernel 2: pair phase. Pure store-bound: 268 MB of writes.
// LESSON (round 2): keep every store instruction WAVE-CONTIGUOUS — lane L
// must write at lane-stride 16 B so one dwordx4 store covers 1 KB of
// consecutive addresses. Regular (L2-routed) stores: that's the path the
// 6.5 TB/s fill kernels use; NT + partial-line patterns regressed 89 µs.
// One block per (b,i) row; thread t covers j = t*4 and j = 1024 + t*4.
// ---------------------------------------------------------------------------
__global__ __launch_bounds__(256) void pair_kernel(
    const float* __restrict__ ss, const float* __restrict__ se,
    const float* __restrict__ bm,
    float* __restrict__ out_valid, float* __restrict__ out_score)
{
    const int row = blockIdx.x;            // row = b*SS + i
    const int b   = row >> 11;
    const int i   = row & (SS - 1);
    const float bmv = bm[0];
    const float s_i = ss[row];             // uniform across block

    const float* seb = se + b * SS;
    const size_t rowoff = (size_t)row * SS;

    #pragma unroll
    for (int half = 0; half < 2; ++half) {
        const int j = half * 1024 + threadIdx.x * 4;   // wave-contiguous
        const float4 e = *(const float4*)(seb + j);

        // match reference add order: (score_s + score_e) + bm
        const float p0 = (s_i + e.x) + bmv;
        const float p1 = (s_i + e.y) + bmv;
        const float p2 = (s_i + e.z) + bmv;
        const float p3 = (s_i + e.w) + bmv;

        const bool v0 = (i <= j    ) && (p0 > 0.0f);
        const bool v1 = (i <= j + 1) && (p1 > 0.0f);
        const bool v2 = (i <= j + 2) && (p2 > 0.0f);
        const bool v3 = (i <= j + 3) && (p3 > 0.0f);

        const float4 vv = make_float4(v0 ? 1.0f : 0.0f, v1 ? 1.0f : 0.0f,
                                      v2 ? 1.0f : 0.0f, v3 ? 1.0f : 0.0f);
        const float4 pv = make_float4(v0 ? p0 : 0.0f, v1 ? p1 : 0.0f,
                                      v2 ? p2 : 0.0f, v3 ? p3 : 0.0f);

        *(float4*)(out_valid + rowoff + j) = vv;
        *(float4*)(out_score + rowoff + j) = pv;
    }
}

extern "C" void kernel_launch(void* const* d_in, const int* in_sizes, int n_in,
                              void* d_out, int out_size, void* d_ws, size_t ws_size,
                              hipStream_t stream) {
    const float* rep  = (const float*)d_in[0];
    const int*   mask = (const int*)  d_in[1];
    const float* Ws   = (const float*)d_in[2];
    const float* bs   = (const float*)d_in[3];
    const float* We   = (const float*)d_in[4];
    const float* be   = (const float*)d_in[5];
    const float* Wm   = (const float*)d_in[6];
    const float* bm   = (const float*)d_in[7];

    float* ss = (float*)d_ws;            // B*S floats
    float* se = ss + BB * SS;            // B*S floats (total 128 KB of ws)

    float* out_valid = (float*)d_out;                          // B*S*S floats
    float* out_score = out_valid + (size_t)BB * SS * SS;       // B*S*S floats

    // Phase 1: 16384 tokens, 1 wave each, 4 waves/block -> 4096 blocks
    token_kernel<<<BB * SS / 4, 256, 0, stream>>>(rep, mask, Ws, bs, We, be,
                                                  Wm, bm, ss, se);

    // Phase 2: one block per (b,i) row -> 16384 blocks x 256 threads
    pair_kernel<<<BB * SS, 256, 0, stream>>>(ss, se, bm, out_valid, out_score);
}